// Round 5
// baseline (216.196 us; speedup 1.0000x reference)
//
#include <hip/hip_runtime.h>
#include <hip/hip_bf16.h>
#include <stdint.h>

// BigBird block-sparse attention, MI355X bf16-MFMA implementation.
// B=2 S=4096 H=768 NH=12 D=64 BLK=64 NB=64 R=3
#define NHD 12
#define SLEN 4096
#define DH 64
#define NBLK 64
#define HDIM 768
#define PEN -10000.0f

typedef __bf16 bf16x8 __attribute__((ext_vector_type(8)));
typedef float f32x4 __attribute__((ext_vector_type(4)));
typedef unsigned short u16x8 __attribute__((ext_vector_type(8)));

__device__ __forceinline__ unsigned short f2bf(float x) {
    union { float f; unsigned u; } v; v.f = x;
    unsigned r = v.u + 0x7fffu + ((v.u >> 16) & 1u);   // RNE
    return (unsigned short)(r >> 16);
}

// ---------------- cast hidden_states f32 -> bf16 ----------------
__global__ void k_cast_hs(const float* __restrict__ in, unsigned short* __restrict__ out, int n8) {
    int i = blockIdx.x * blockDim.x + threadIdx.x;
    if (i >= n8) return;
    const float4* p = (const float4*)in + (size_t)i * 2;
    float4 a = p[0], b = p[1];
    u16x8 o;
    o[0]=f2bf(a.x); o[1]=f2bf(a.y); o[2]=f2bf(a.z); o[3]=f2bf(a.w);
    o[4]=f2bf(b.x); o[5]=f2bf(b.y); o[6]=f2bf(b.z); o[7]=f2bf(b.w);
    ((u16x8*)out)[i] = o;
}

// ---------------- W (k,n) f32 -> Wt (n,k) bf16 ----------------
__global__ void k_wt(const float* __restrict__ Wq, const float* __restrict__ Wk,
                     const float* __restrict__ Wv, unsigned short* __restrict__ wt) {
    const float* W = blockIdx.z == 0 ? Wq : (blockIdx.z == 1 ? Wk : Wv);
    unsigned short* out = wt + (size_t)blockIdx.z * HDIM * HDIM;
    __shared__ float tile[64][65];
    int t = threadIdx.x;
    int k0 = blockIdx.x * 64, n0 = blockIdx.y * 64;
    int r = t >> 2, c4 = t & 3;
#pragma unroll
    for (int j = 0; j < 16; j += 4) {
        float4 v = *(const float4*)&W[(size_t)(k0 + r) * HDIM + n0 + c4 * 16 + j];
        tile[r][c4*16+j+0] = v.x; tile[r][c4*16+j+1] = v.y;
        tile[r][c4*16+j+2] = v.z; tile[r][c4*16+j+3] = v.w;
    }
    __syncthreads();
    u16x8 o0, o1;
#pragma unroll
    for (int j = 0; j < 8; ++j) o0[j] = f2bf(tile[c4*16 + j][r]);
#pragma unroll
    for (int j = 0; j < 8; ++j) o1[j] = f2bf(tile[c4*16 + 8 + j][r]);
    *(u16x8*)&out[(size_t)(n0 + r) * HDIM + k0 + c4*16]     = o0;
    *(u16x8*)&out[(size_t)(n0 + r) * HDIM + k0 + c4*16 + 8] = o1;
}

// ---------------- projection GEMM: (8192x768)x(768x768) bf16 MFMA ----------------
__global__ __launch_bounds__(256) void k_proj(const unsigned short* __restrict__ hsb,
                                              const unsigned short* __restrict__ wtb,
                                              unsigned short* __restrict__ qkv) {
    __shared__ unsigned short As[128][72];
    __shared__ unsigned short Bs[128][72];
    const unsigned short* Bw = wtb + (size_t)blockIdx.z * HDIM * HDIM;
    unsigned short* out = qkv + (size_t)blockIdx.z * (2u * NHD * SLEN * DH);
    int m0 = blockIdx.x * 128, n0 = blockIdx.y * 128;
    int t = threadIdx.x;
    int w = t >> 6, l = t & 63, g = l >> 4, c = l & 15;
    int wm = w >> 1, wn = w & 1;
    int sr = t >> 1, sh = (t & 1) * 32;
    f32x4 acc[4][4];
#pragma unroll
    for (int i = 0; i < 4; ++i)
#pragma unroll
        for (int j = 0; j < 4; ++j) acc[i][j] = (f32x4){0.f,0.f,0.f,0.f};

    for (int kt = 0; kt < HDIM; kt += 64) {
        __syncthreads();
#pragma unroll
        for (int j = 0; j < 4; ++j) {
            *(u16x8*)&As[sr][sh + 8*j] = *(const u16x8*)&hsb[(size_t)(m0 + sr) * HDIM + kt + sh + 8*j];
            *(u16x8*)&Bs[sr][sh + 8*j] = *(const u16x8*)&Bw[(size_t)(n0 + sr) * HDIM + kt + sh + 8*j];
        }
        __syncthreads();
#pragma unroll
        for (int ks = 0; ks < 2; ++ks) {
            bf16x8 af[4], bf_[4];
#pragma unroll
            for (int mt = 0; mt < 4; ++mt) af[mt]  = *(const bf16x8*)&As[64*wm + 16*mt + c][32*ks + 8*g];
#pragma unroll
            for (int nt = 0; nt < 4; ++nt) bf_[nt] = *(const bf16x8*)&Bs[64*wn + 16*nt + c][32*ks + 8*g];
#pragma unroll
            for (int mt = 0; mt < 4; ++mt)
#pragma unroll
                for (int nt = 0; nt < 4; ++nt)
                    acc[mt][nt] = __builtin_amdgcn_mfma_f32_16x16x32_bf16(af[mt], bf_[nt], acc[mt][nt], 0, 0, 0);
        }
    }
#pragma unroll
    for (int mt = 0; mt < 4; ++mt)
#pragma unroll
        for (int nt = 0; nt < 4; ++nt)
#pragma unroll
            for (int r2 = 0; r2 < 4; ++r2) {
                int m = m0 + 64*wm + 16*mt + 4*g + r2;
                int n = n0 + 64*wn + 16*nt + c;
                int bb = m >> 12, s = m & 4095;
                int hh = n >> 6,  d = n & 63;
                out[(((size_t)bb * NHD + hh) * SLEN + s) * DH + d] = f2bf(acc[mt][nt][r2]);
            }
}

// ---------------- V (bh,s,d) -> VT (bh,d,s) bf16 ----------------
__global__ void k_vtrans(const unsigned short* __restrict__ v, unsigned short* __restrict__ vt) {
    __shared__ unsigned tile[64][65];
    int bh = blockIdx.y;
    int s0 = blockIdx.x * 64;
    int t = threadIdx.x;
    int r = t >> 2, c4 = t & 3;
    const unsigned short* vb = v + (size_t)bh * SLEN * DH;
#pragma unroll
    for (int jj = 0; jj < 16; jj += 8) {
        u16x8 x = *(const u16x8*)&vb[(size_t)(s0 + r) * DH + c4*16 + jj];
#pragma unroll
        for (int e = 0; e < 8; ++e) tile[r][c4*16 + jj + e] = x[e];
    }
    __syncthreads();
    unsigned short* vto = vt + (size_t)bh * DH * SLEN;
    int d = t >> 2;
    u16x8 o0, o1;
#pragma unroll
    for (int j = 0; j < 8; ++j) o0[j] = (unsigned short)tile[c4*16 + j][d];
#pragma unroll
    for (int j = 0; j < 8; ++j) o1[j] = (unsigned short)tile[c4*16 + 8 + j][d];
    *(u16x8*)&vto[(size_t)d * SLEN + s0 + c4*16]     = o0;
    *(u16x8*)&vto[(size_t)d * SLEN + s0 + c4*16 + 8] = o1;
}

// ---------------- flash-style block-sparse attention (v4) ----------------
// grid = 1536 = 24 bh x 64 rows (rows 0/63 first: ord 0->row0, 1->row63,
// k->row k-1). 256 threads = 4 independent waves; wave wq owns 16 q-rows,
// iterates over the row's key-blocks with online (defer-max) softmax.
// ZERO __syncthreads. P redistribution via wave-private XOR-swizzled LDS.
__global__ __launch_bounds__(256) void k_attn(
    const unsigned short* __restrict__ Qb, const unsigned short* __restrict__ Kb,
    const unsigned short* __restrict__ VTb,
    const int* __restrict__ rand_attn,
    const float* __restrict__ band_mask, const float* __restrict__ from_mask,
    const float* __restrict__ to_mask, const float* __restrict__ fbm,
    const float* __restrict__ tbm,
    float* __restrict__ out)
{
    __shared__ __align__(16) char plds[4 * 2048];   // 2KB per wave, wave-private

    int i0 = blockIdx.x;
    int bh = i0 % 24, ord = i0 / 24;
    int row = (ord == 0) ? 0 : (ord == 1) ? 63 : (ord - 1);
    int b = bh / NHD, h = bh - b * NHD;
    int t = threadIdx.x;
    int wq = t >> 6, l = t & 63, g = l >> 4, c = l & 15;

    size_t bhoff = (size_t)bh * SLEN * DH;
    const unsigned short* VTp = VTb + (size_t)bh * DH * SLEN;
    int q0 = row * 64 + wq * 16;              // this wave's first q row

    // Q fragments (held in registers whole kernel)
    bf16x8 qf[2];
#pragma unroll
    for (int kk = 0; kk < 2; ++kk)
        qf[kk] = *(const bf16x8*)&Qb[bhoff + (size_t)(q0 + c) * DH + kk * 32 + 8 * g];

    // per-block hoisted scalars
    float fmq = fbm[(b * NBLK + row) * 64 + wq * 16 + c];          // from_blocked for rand mask
    size_t bm_base = ((size_t)(b * 60 + row - 2) * 64 + (wq * 16 + c)) * 192;  // band (middle only)
    int tm_base = b * SLEN;

    // online-softmax state (per lane: q = q0 + c, replicated across g)
    float m_run = -1e30f, l_run = 0.f;
    f32x4 o_acc[4];
#pragma unroll
    for (int dt = 0; dt < 4; ++dt) o_acc[dt] = (f32x4){0.f,0.f,0.f,0.f};

    char* myl = plds + wq * 2048 + c * 128;
    int swz = (c & 7) << 4;

    auto step = [&](int blk, int kv, int sb) __attribute__((always_inline)) {
        // ---- K frags + V frags + mask loads all issued up front ----
        const unsigned short* Kp = Kb + bhoff + (size_t)blk * 64 * DH;
        bf16x8 kf[4][2];
#pragma unroll
        for (int mt = 0; mt < 4; ++mt)
#pragma unroll
            for (int kk = 0; kk < 2; ++kk)
                kf[mt][kk] = *(const bf16x8*)&Kp[(size_t)(mt * 16 + c) * DH + kk * 32 + 8 * g];
        bf16x8 vf[4][2];
#pragma unroll
        for (int dt = 0; dt < 4; ++dt)
#pragma unroll
            for (int kk = 0; kk < 2; ++kk)
                vf[dt][kk] = *(const bf16x8*)&VTp[(size_t)(dt * 16 + c) * SLEN + blk * 64 + kk * 32 + 8 * g];
        float mk[4][4];
        if (kv == 0) {
#pragma unroll
            for (int mt = 0; mt < 4; ++mt)
#pragma unroll
                for (int r2 = 0; r2 < 4; ++r2)
                    mk[mt][r2] = to_mask[tm_base + blk * 64 + mt * 16 + 4 * g + r2];
        } else if (kv == 1) {
#pragma unroll
            for (int mt = 0; mt < 4; ++mt)
#pragma unroll
                for (int r2 = 0; r2 < 4; ++r2)
                    mk[mt][r2] = band_mask[bm_base + sb + mt * 16 + 4 * g + r2];
        } else {
#pragma unroll
            for (int mt = 0; mt < 4; ++mt)
#pragma unroll
                for (int r2 = 0; r2 < 4; ++r2)
                    mk[mt][r2] = fmq * tbm[(size_t)(b * NBLK + blk) * 64 + mt * 16 + 4 * g + r2];
        }

        // ---- S^T = K * Q^T  (64 keys x 16 q) ----
        f32x4 sa[4];
#pragma unroll
        for (int mt = 0; mt < 4; ++mt) sa[mt] = (f32x4){0.f,0.f,0.f,0.f};
#pragma unroll
        for (int kk = 0; kk < 2; ++kk)
#pragma unroll
            for (int mt = 0; mt < 4; ++mt)
                sa[mt] = __builtin_amdgcn_mfma_f32_16x16x32_bf16(kf[mt][kk], qf[kk], sa[mt], 0, 0, 0);

        // ---- scale + penalty ----
#pragma unroll
        for (int mt = 0; mt < 4; ++mt)
#pragma unroll
            for (int r2 = 0; r2 < 4; ++r2)
                sa[mt][r2] = sa[mt][r2] * 0.125f + (1.f - mk[mt][r2]) * PEN;

        // ---- online softmax (defer-max, THR=8) ----
        float pm = -1e30f;
#pragma unroll
        for (int mt = 0; mt < 4; ++mt)
#pragma unroll
            for (int r2 = 0; r2 < 4; ++r2) pm = fmaxf(pm, sa[mt][r2]);
        pm = fmaxf(pm, __shfl_xor(pm, 16));
        pm = fmaxf(pm, __shfl_xor(pm, 32));
        bool need = pm > m_run + 8.f;
        float mnew = need ? pm : m_run;
        float scale = __expf(m_run - mnew);        // ==1 when !need
        m_run = mnew;
        l_run *= scale;
#pragma unroll
        for (int dt = 0; dt < 4; ++dt)
#pragma unroll
            for (int r2 = 0; r2 < 4; ++r2) o_acc[dt][r2] *= scale;

        float rs = 0.f;
#pragma unroll
        for (int mt = 0; mt < 4; ++mt)
#pragma unroll
            for (int r2 = 0; r2 < 4; ++r2) {
                float e = __expf(sa[mt][r2] - m_run);
                sa[mt][r2] = e;
                rs += e;
            }
        rs += __shfl_xor(rs, 16);
        rs += __shfl_xor(rs, 32);
        l_run += rs;

        // ---- pack P -> wave-private LDS (XOR swizzle), read back as B-frags ----
#pragma unroll
        for (int mt = 0; mt < 4; ++mt) {
            unsigned lo = (unsigned)f2bf(sa[mt][0]) | ((unsigned)f2bf(sa[mt][1]) << 16);
            unsigned hi = (unsigned)f2bf(sa[mt][2]) | ((unsigned)f2bf(sa[mt][3]) << 16);
            unsigned long long pk = (unsigned long long)lo | ((unsigned long long)hi << 32);
            *(unsigned long long*)(myl + ((mt * 32 + g * 8) ^ swz)) = pk;
        }
        asm volatile("" ::: "memory");     // keep write before read (same-wave DS is ordered)
        bf16x8 pf0 = *(const bf16x8*)(myl + ((g * 16) ^ swz));
        bf16x8 pf1 = *(const bf16x8*)(myl + ((64 + g * 16) ^ swz));

        // ---- O^T += V^T * P  (64 d x 16 q) ----
#pragma unroll
        for (int dt = 0; dt < 4; ++dt)
            o_acc[dt] = __builtin_amdgcn_mfma_f32_16x16x32_bf16(vf[dt][0], pf0, o_acc[dt], 0, 0, 0);
#pragma unroll
        for (int dt = 0; dt < 4; ++dt)
            o_acc[dt] = __builtin_amdgcn_mfma_f32_16x16x32_bf16(vf[dt][1], pf1, o_acc[dt], 0, 0, 0);
    };

    if (row == 0 || row == 63) {
        for (int it = 0; it < NBLK; ++it) step(it, 0, 0);
    } else {
        int rbase = ((b * NHD + h) * 62 + (row - 1)) * 3;
        int r0 = rand_attn[rbase], r1 = rand_attn[rbase + 1], r2v = rand_attn[rbase + 2];
        int nkb = (row == 1 || row == 62) ? 7 : 8;
        for (int j = 0; j < nkb; ++j) {
            int blk, kv, sb = 0;
            if (row == 1) {
                blk = j==0?0 : j==1?1 : j==2?2 : j==3?63 : j==4?r0 : j==5?r1 : r2v;
                kv = j < 4 ? 0 : 2;
            } else if (row == 62) {
                blk = j==0?0 : j==1?61 : j==2?62 : j==3?63 : j==4?r0 : j==5?r1 : r2v;
                kv = j < 4 ? 0 : 2;
            } else {
                blk = j==0?0 : j==1?(row-1) : j==2?row : j==3?(row+1) : j==4?r0 : j==5?r1 : j==6?r2v : 63;
                kv = (j >= 1 && j <= 3) ? 1 : (j >= 4 && j <= 6) ? 2 : 0;
                sb = j==1?0 : j==2?64 : j==3?128 : 0;
            }
            step(blk, kv, sb);
        }
    }

    // ---- output: O[d][q]/l * from_mask ----
    int s = q0 + c;
    float fm = from_mask[b * SLEN + s];
    float inv = fm / l_run;
    size_t obase = ((size_t)b * SLEN + s) * HDIM + h * DH;
#pragma unroll
    for (int dt = 0; dt < 4; ++dt) {
        float4 val;
        val.x = o_acc[dt][0] * inv;
        val.y = o_acc[dt][1] * inv;
        val.z = o_acc[dt][2] * inv;
        val.w = o_acc[dt][3] * inv;
        *(float4*)&out[obase + dt * 16 + 4 * g] = val;
    }
}

extern "C" void kernel_launch(void* const* d_in, const int* in_sizes, int n_in,
                              void* d_out, int out_size, void* d_ws, size_t ws_size,
                              hipStream_t stream) {
    const float* hs    = (const float*)d_in[0];
    const float* Wq    = (const float*)d_in[1];
    const float* Wk    = (const float*)d_in[2];
    const float* Wv    = (const float*)d_in[3];
    const float* band  = (const float*)d_in[4];
    const float* fromm = (const float*)d_in[5];
    const float* tom   = (const float*)d_in[6];
    const float* fbm   = (const float*)d_in[7];
    const float* tbm   = (const float*)d_in[8];
    const int*   ra    = (const int*)d_in[9];      // harness passes integers as int32
    float* out = (float*)d_out;

    // workspace layout (bytes):
    //  [0, 12.58M)  hsb  (bf16 hidden)  -> reused by vtb after proj
    //  [12.58M, 16.12M) wtb (3x768x768 bf16)
    //  [16.12M, 53.87M) qkv (3 x (B,NH,S,D) bf16)
    char* ws = (char*)d_ws;
    unsigned short* hsb = (unsigned short*)(ws);
    unsigned short* vtb = (unsigned short*)(ws);                 // reuse (proj done before vtrans)
    unsigned short* wtb = (unsigned short*)(ws + 12582912);
    unsigned short* qkv = (unsigned short*)(ws + 16121856);

    k_cast_hs<<<3072, 256, 0, stream>>>(hs, hsb, 786432);
    k_wt<<<dim3(12, 12, 3), 256, 0, stream>>>(Wq, Wk, Wv, wtb);
    k_proj<<<dim3(64, 6, 3), 256, 0, stream>>>(hsb, wtb, qkv);
    k_vtrans<<<dim3(64, 24), 256, 0, stream>>>(qkv + 2 * 6291456, vtb);
    k_attn<<<1536, 256, 0, stream>>>(qkv, qkv + 6291456, vtb, ra,
                                     band, fromm, tom, fbm, tbm, out);
}

// Round 6
// 199.949 us; speedup vs baseline: 1.0813x; 1.0813x over previous
//
#include <hip/hip_runtime.h>
#include <hip/hip_bf16.h>
#include <stdint.h>

// BigBird block-sparse attention, MI355X bf16-MFMA implementation.
// B=2 S=4096 H=768 NH=12 D=64 BLK=64 NB=64 R=3
#define NHD 12
#define SLEN 4096
#define DH 64
#define NBLK 64
#define HDIM 768
#define PEN -10000.0f

typedef __bf16 bf16x8 __attribute__((ext_vector_type(8)));
typedef float f32x4 __attribute__((ext_vector_type(4)));
typedef unsigned short u16x8 __attribute__((ext_vector_type(8)));

__device__ __forceinline__ unsigned short f2bf(float x) {
    union { float f; unsigned u; } v; v.f = x;
    unsigned r = v.u + 0x7fffu + ((v.u >> 16) & 1u);   // RNE
    return (unsigned short)(r >> 16);
}

// ---------------- cast hidden_states f32 -> bf16 ----------------
__global__ void k_cast_hs(const float* __restrict__ in, unsigned short* __restrict__ out, int n8) {
    int i = blockIdx.x * blockDim.x + threadIdx.x;
    if (i >= n8) return;
    const float4* p = (const float4*)in + (size_t)i * 2;
    float4 a = p[0], b = p[1];
    u16x8 o;
    o[0]=f2bf(a.x); o[1]=f2bf(a.y); o[2]=f2bf(a.z); o[3]=f2bf(a.w);
    o[4]=f2bf(b.x); o[5]=f2bf(b.y); o[6]=f2bf(b.z); o[7]=f2bf(b.w);
    ((u16x8*)out)[i] = o;
}

// ---------------- W (k,n) f32 -> Wt (n,k) bf16 ----------------
__global__ void k_wt(const float* __restrict__ Wq, const float* __restrict__ Wk,
                     const float* __restrict__ Wv, unsigned short* __restrict__ wt) {
    const float* W = blockIdx.z == 0 ? Wq : (blockIdx.z == 1 ? Wk : Wv);
    unsigned short* out = wt + (size_t)blockIdx.z * HDIM * HDIM;
    __shared__ float tile[64][65];
    int t = threadIdx.x;
    int k0 = blockIdx.x * 64, n0 = blockIdx.y * 64;
    int r = t >> 2, c4 = t & 3;
#pragma unroll
    for (int j = 0; j < 16; j += 4) {
        float4 v = *(const float4*)&W[(size_t)(k0 + r) * HDIM + n0 + c4 * 16 + j];
        tile[r][c4*16+j+0] = v.x; tile[r][c4*16+j+1] = v.y;
        tile[r][c4*16+j+2] = v.z; tile[r][c4*16+j+3] = v.w;
    }
    __syncthreads();
    u16x8 o0, o1;
#pragma unroll
    for (int j = 0; j < 8; ++j) o0[j] = f2bf(tile[c4*16 + j][r]);
#pragma unroll
    for (int j = 0; j < 8; ++j) o1[j] = f2bf(tile[c4*16 + 8 + j][r]);
    *(u16x8*)&out[(size_t)(n0 + r) * HDIM + k0 + c4*16]     = o0;
    *(u16x8*)&out[(size_t)(n0 + r) * HDIM + k0 + c4*16 + 8] = o1;
}

// ---------------- projection GEMM: (8192x768)x(768x768) bf16 MFMA ----------------
__global__ __launch_bounds__(256) void k_proj(const unsigned short* __restrict__ hsb,
                                              const unsigned short* __restrict__ wtb,
                                              unsigned short* __restrict__ qkv) {
    __shared__ unsigned short As[128][72];
    __shared__ unsigned short Bs[128][72];
    const unsigned short* Bw = wtb + (size_t)blockIdx.z * HDIM * HDIM;
    unsigned short* out = qkv + (size_t)blockIdx.z * (2u * NHD * SLEN * DH);
    int m0 = blockIdx.x * 128, n0 = blockIdx.y * 128;
    int t = threadIdx.x;
    int w = t >> 6, l = t & 63, g = l >> 4, c = l & 15;
    int wm = w >> 1, wn = w & 1;
    int sr = t >> 1, sh = (t & 1) * 32;
    f32x4 acc[4][4];
#pragma unroll
    for (int i = 0; i < 4; ++i)
#pragma unroll
        for (int j = 0; j < 4; ++j) acc[i][j] = (f32x4){0.f,0.f,0.f,0.f};

    for (int kt = 0; kt < HDIM; kt += 64) {
        __syncthreads();
#pragma unroll
        for (int j = 0; j < 4; ++j) {
            *(u16x8*)&As[sr][sh + 8*j] = *(const u16x8*)&hsb[(size_t)(m0 + sr) * HDIM + kt + sh + 8*j];
            *(u16x8*)&Bs[sr][sh + 8*j] = *(const u16x8*)&Bw[(size_t)(n0 + sr) * HDIM + kt + sh + 8*j];
        }
        __syncthreads();
#pragma unroll
        for (int ks = 0; ks < 2; ++ks) {
            bf16x8 af[4], bf_[4];
#pragma unroll
            for (int mt = 0; mt < 4; ++mt) af[mt]  = *(const bf16x8*)&As[64*wm + 16*mt + c][32*ks + 8*g];
#pragma unroll
            for (int nt = 0; nt < 4; ++nt) bf_[nt] = *(const bf16x8*)&Bs[64*wn + 16*nt + c][32*ks + 8*g];
#pragma unroll
            for (int mt = 0; mt < 4; ++mt)
#pragma unroll
                for (int nt = 0; nt < 4; ++nt)
                    acc[mt][nt] = __builtin_amdgcn_mfma_f32_16x16x32_bf16(af[mt], bf_[nt], acc[mt][nt], 0, 0, 0);
        }
    }
#pragma unroll
    for (int mt = 0; mt < 4; ++mt)
#pragma unroll
        for (int nt = 0; nt < 4; ++nt)
#pragma unroll
            for (int r2 = 0; r2 < 4; ++r2) {
                int m = m0 + 64*wm + 16*mt + 4*g + r2;
                int n = n0 + 64*wn + 16*nt + c;
                int bb = m >> 12, s = m & 4095;
                int hh = n >> 6,  d = n & 63;
                out[(((size_t)bb * NHD + hh) * SLEN + s) * DH + d] = f2bf(acc[mt][nt][r2]);
            }
}

// ---------------- V (bh,s,d) -> VT (bh,d,s) bf16 ----------------
__global__ void k_vtrans(const unsigned short* __restrict__ v, unsigned short* __restrict__ vt) {
    __shared__ unsigned tile[64][65];
    int bh = blockIdx.y;
    int s0 = blockIdx.x * 64;
    int t = threadIdx.x;
    int r = t >> 2, c4 = t & 3;
    const unsigned short* vb = v + (size_t)bh * SLEN * DH;
#pragma unroll
    for (int jj = 0; jj < 16; jj += 8) {
        u16x8 x = *(const u16x8*)&vb[(size_t)(s0 + r) * DH + c4*16 + jj];
#pragma unroll
        for (int e = 0; e < 8; ++e) tile[r][c4*16 + jj + e] = x[e];
    }
    __syncthreads();
    unsigned short* vto = vt + (size_t)bh * DH * SLEN;
    int d = t >> 2;
    u16x8 o0, o1;
#pragma unroll
    for (int j = 0; j < 8; ++j) o0[j] = (unsigned short)tile[c4*16 + j][d];
#pragma unroll
    for (int j = 0; j < 8; ++j) o1[j] = (unsigned short)tile[c4*16 + 8 + j][d];
    *(u16x8*)&vto[(size_t)d * SLEN + s0 + c4*16]     = o0;
    *(u16x8*)&vto[(size_t)d * SLEN + s0 + c4*16 + 8] = o1;
}

// ---------------- flash-style block-sparse attention (v5) ----------------
// v4's barrier-free 4-wave structure + UNIFORM 8-step tasks: rows 0/63 are
// split into 8 online-softmax partials (combine kernel merges). grid =
// 24 bh x 78 tasks = 1872, XCD-swizzled. No block runs >8 steps -> no
// serial tail (v4: 48 blocks ran 64 steps and set the duration).
// Masks loaded as float4 (contiguous in r2).
__global__ __launch_bounds__(256) void k_attn(
    const unsigned short* __restrict__ Qb, const unsigned short* __restrict__ Kb,
    const unsigned short* __restrict__ VTb,
    const int* __restrict__ rand_attn,
    const float* __restrict__ band_mask, const float* __restrict__ from_mask,
    const float* __restrict__ to_mask, const float* __restrict__ fbm,
    const float* __restrict__ tbm,
    float* __restrict__ out, float* __restrict__ partials)
{
    __shared__ __align__(16) char plds[4 * 2048];   // 2KB per wave, wave-private

    int i0 = blockIdx.x;
    int gid = (i0 & 7) * 234 + (i0 >> 3);           // XCD swizzle (1872 = 8*234)
    int bh = gid / 78, task = gid - bh * 78;
    int b = bh / NHD, h = bh - b * NHD;
    int t = threadIdx.x;
    int wq = t >> 6, l = t & 63, g = l >> 4, c = l & 15;

    // ---- task -> 8 step descriptors (kv: 0=to_mask 1=band 2=rand 3=skip) ----
    int row, mode = 0, pslot = 0;
    int blkj[8], kvj[8], sbj[8];
#pragma unroll
    for (int j = 0; j < 8; ++j) sbj[j] = 0;
    if (task < 8) {
        row = 0; mode = 1; pslot = task;
#pragma unroll
        for (int j = 0; j < 8; ++j) { blkj[j] = task * 8 + j; kvj[j] = 0; }
    } else if (task >= 70) {
        row = 63; mode = 1; pslot = task - 70;
#pragma unroll
        for (int j = 0; j < 8; ++j) { blkj[j] = pslot * 8 + j; kvj[j] = 0; }
    } else {
        row = task - 7;                              // 1..62
        int rbase = ((b * NHD + h) * 62 + (row - 1)) * 3;
        blkj[4] = rand_attn[rbase];
        blkj[5] = rand_attn[rbase + 1];
        blkj[6] = rand_attn[rbase + 2];
        kvj[4] = kvj[5] = kvj[6] = 2;
        blkj[0] = 0; kvj[0] = 0;
        if (row == 1) {
            blkj[1]=1;  blkj[2]=2;  blkj[3]=63; kvj[1]=kvj[2]=kvj[3]=0;
            blkj[7]=0;  kvj[7]=3;
        } else if (row == 62) {
            blkj[1]=61; blkj[2]=62; blkj[3]=63; kvj[1]=kvj[2]=kvj[3]=0;
            blkj[7]=0;  kvj[7]=3;
        } else {
            blkj[1]=row-1; blkj[2]=row; blkj[3]=row+1;
            kvj[1]=kvj[2]=kvj[3]=1; sbj[1]=0; sbj[2]=64; sbj[3]=128;
            blkj[7]=63; kvj[7]=0;
        }
    }

    size_t bhoff = (size_t)bh * SLEN * DH;
    const unsigned short* VTp = VTb + (size_t)bh * DH * SLEN;
    int q0 = row * 64 + wq * 16;                     // this wave's first q row

    // Q fragments (held in registers whole kernel)
    bf16x8 qf[2];
#pragma unroll
    for (int kk = 0; kk < 2; ++kk)
        qf[kk] = *(const bf16x8*)&Qb[bhoff + (size_t)(q0 + c) * DH + kk * 32 + 8 * g];

    float fmq = fbm[(b * NBLK + row) * 64 + wq * 16 + c];
    size_t bm_base = ((size_t)(b * 60 + row - 2) * 64 + (wq * 16 + c)) * 192;  // deref only if kv==1
    int tm_base = b * SLEN;

    // online-softmax state (per lane: q = q0 + c, replicated across g)
    float m_run = -1e30f, l_run = 0.f;
    f32x4 o_acc[4];
#pragma unroll
    for (int dt = 0; dt < 4; ++dt) o_acc[dt] = (f32x4){0.f,0.f,0.f,0.f};

    char* myl = plds + wq * 2048 + c * 128;
    int swz = (c & 7) << 4;

    auto step = [&](int blk, int kv, int sb) __attribute__((always_inline)) {
        // ---- K frags + V frags + mask (float4) loads issued up front ----
        const unsigned short* Kp = Kb + bhoff + (size_t)blk * 64 * DH;
        bf16x8 kf[4][2];
#pragma unroll
        for (int mt = 0; mt < 4; ++mt)
#pragma unroll
            for (int kk = 0; kk < 2; ++kk)
                kf[mt][kk] = *(const bf16x8*)&Kp[(size_t)(mt * 16 + c) * DH + kk * 32 + 8 * g];
        bf16x8 vf[4][2];
#pragma unroll
        for (int dt = 0; dt < 4; ++dt)
#pragma unroll
            for (int kk = 0; kk < 2; ++kk)
                vf[dt][kk] = *(const bf16x8*)&VTp[(size_t)(dt * 16 + c) * SLEN + blk * 64 + kk * 32 + 8 * g];
        float4 mk[4];
        if (kv == 0) {
#pragma unroll
            for (int mt = 0; mt < 4; ++mt)
                mk[mt] = *(const float4*)&to_mask[tm_base + blk * 64 + mt * 16 + 4 * g];
        } else if (kv == 1) {
#pragma unroll
            for (int mt = 0; mt < 4; ++mt)
                mk[mt] = *(const float4*)&band_mask[bm_base + sb + mt * 16 + 4 * g];
        } else {
#pragma unroll
            for (int mt = 0; mt < 4; ++mt) {
                float4 tb = *(const float4*)&tbm[(size_t)(b * NBLK + blk) * 64 + mt * 16 + 4 * g];
                mk[mt].x = fmq * tb.x; mk[mt].y = fmq * tb.y;
                mk[mt].z = fmq * tb.z; mk[mt].w = fmq * tb.w;
            }
        }

        // ---- S^T = K * Q^T  (64 keys x 16 q) ----
        f32x4 sa[4];
#pragma unroll
        for (int mt = 0; mt < 4; ++mt) sa[mt] = (f32x4){0.f,0.f,0.f,0.f};
#pragma unroll
        for (int kk = 0; kk < 2; ++kk)
#pragma unroll
            for (int mt = 0; mt < 4; ++mt)
                sa[mt] = __builtin_amdgcn_mfma_f32_16x16x32_bf16(kf[mt][kk], qf[kk], sa[mt], 0, 0, 0);

        // ---- scale + penalty ----
#pragma unroll
        for (int mt = 0; mt < 4; ++mt) {
            sa[mt][0] = sa[mt][0] * 0.125f + (1.f - mk[mt].x) * PEN;
            sa[mt][1] = sa[mt][1] * 0.125f + (1.f - mk[mt].y) * PEN;
            sa[mt][2] = sa[mt][2] * 0.125f + (1.f - mk[mt].z) * PEN;
            sa[mt][3] = sa[mt][3] * 0.125f + (1.f - mk[mt].w) * PEN;
        }

        // ---- online softmax (defer-max, THR=8) ----
        float pm = -1e30f;
#pragma unroll
        for (int mt = 0; mt < 4; ++mt)
#pragma unroll
            for (int r2 = 0; r2 < 4; ++r2) pm = fmaxf(pm, sa[mt][r2]);
        pm = fmaxf(pm, __shfl_xor(pm, 16));
        pm = fmaxf(pm, __shfl_xor(pm, 32));
        bool need = pm > m_run + 8.f;
        float mnew = need ? pm : m_run;
        float scale = __expf(m_run - mnew);        // ==1 when !need
        m_run = mnew;
        l_run *= scale;
#pragma unroll
        for (int dt = 0; dt < 4; ++dt)
#pragma unroll
            for (int r2 = 0; r2 < 4; ++r2) o_acc[dt][r2] *= scale;

        float rs = 0.f;
#pragma unroll
        for (int mt = 0; mt < 4; ++mt)
#pragma unroll
            for (int r2 = 0; r2 < 4; ++r2) {
                float e = __expf(sa[mt][r2] - m_run);
                sa[mt][r2] = e;
                rs += e;
            }
        rs += __shfl_xor(rs, 16);
        rs += __shfl_xor(rs, 32);
        l_run += rs;

        // ---- pack P -> wave-private LDS (XOR swizzle), read back as B-frags ----
#pragma unroll
        for (int mt = 0; mt < 4; ++mt) {
            unsigned lo = (unsigned)f2bf(sa[mt][0]) | ((unsigned)f2bf(sa[mt][1]) << 16);
            unsigned hi = (unsigned)f2bf(sa[mt][2]) | ((unsigned)f2bf(sa[mt][3]) << 16);
            unsigned long long pk = (unsigned long long)lo | ((unsigned long long)hi << 32);
            *(unsigned long long*)(myl + ((mt * 32 + g * 8) ^ swz)) = pk;
        }
        asm volatile("" ::: "memory");     // keep write before read (same-wave DS is ordered)
        bf16x8 pf0 = *(const bf16x8*)(myl + ((g * 16) ^ swz));
        bf16x8 pf1 = *(const bf16x8*)(myl + ((64 + g * 16) ^ swz));

        // ---- O^T += V^T * P  (64 d x 16 q) ----
#pragma unroll
        for (int dt = 0; dt < 4; ++dt)
            o_acc[dt] = __builtin_amdgcn_mfma_f32_16x16x32_bf16(vf[dt][0], pf0, o_acc[dt], 0, 0, 0);
#pragma unroll
        for (int dt = 0; dt < 4; ++dt)
            o_acc[dt] = __builtin_amdgcn_mfma_f32_16x16x32_bf16(vf[dt][1], pf1, o_acc[dt], 0, 0, 0);
    };

#pragma unroll
    for (int j = 0; j < 8; ++j) {
        if (kvj[j] != 3)
            step(blkj[j], kvj[j], sbj[j]);
    }

    if (mode == 0) {
        // ---- output: O[d][q]/l * from_mask ----
        int s = q0 + c;
        float fm = from_mask[b * SLEN + s];
        float inv = fm / l_run;
        size_t obase = ((size_t)b * SLEN + s) * HDIM + h * DH;
#pragma unroll
        for (int dt = 0; dt < 4; ++dt) {
            float4 val;
            val.x = o_acc[dt][0] * inv;
            val.y = o_acc[dt][1] * inv;
            val.z = o_acc[dt][2] * inv;
            val.w = o_acc[dt][3] * inv;
            *(float4*)&out[obase + dt * 16 + 4 * g] = val;
        }
    } else {
        // ---- partial: raw o, m, l ----
        float* pb = partials + (size_t)((bh * 2 + (row == 63 ? 1 : 0)) * 8 + pslot) * 4224;
        int q = wq * 16 + c;
#pragma unroll
        for (int dt = 0; dt < 4; ++dt) {
            float4 val;
            val.x = o_acc[dt][0]; val.y = o_acc[dt][1];
            val.z = o_acc[dt][2]; val.w = o_acc[dt][3];
            *(float4*)&pb[q * 64 + dt * 16 + 4 * g] = val;
        }
        if (g == 0) {
            pb[4096 + q] = m_run;
            pb[4160 + q] = l_run;
        }
    }
}

// ---------------- combine 8 partials for row-blocks 0 and 63 ----------------
// partial o_i is raw (unnormalized); weight by exp(m_i - M), L = sum l_i w_i.
__global__ void k_combine(const float* __restrict__ partials, const float* __restrict__ from_mask,
                          float* __restrict__ out) {
    int gid = blockIdx.x;          // 48 = bh*2 + rb
    int bh = gid >> 1, rb = gid & 1;
    int b = bh / NHD, h = bh - b * NHD;
    int t = threadIdx.x;           // 256
    int q = t >> 2, dc = (t & 3) * 16;
    const float* base = partials + (size_t)gid * 8 * 4224;
    float M = -1e30f;
#pragma unroll
    for (int i = 0; i < 8; ++i) M = fmaxf(M, base[i*4224 + 4096 + q]);
    float L = 0.f, cx[16];
#pragma unroll
    for (int j = 0; j < 16; ++j) cx[j] = 0.f;
    for (int i = 0; i < 8; ++i) {
        float w = __expf(base[i*4224 + 4096 + q] - M);
        L += base[i*4224 + 4160 + q] * w;
#pragma unroll
        for (int j = 0; j < 16; ++j) cx[j] += base[i*4224 + q*64 + dc + j] * w;
    }
    int s = (rb ? 4032 : 0) + q;
    float fm = from_mask[b * SLEN + s];
    float inv = fm / L;
#pragma unroll
    for (int j = 0; j < 16; ++j)
        out[((size_t)b * SLEN + s) * HDIM + h * DH + dc + j] = cx[j] * inv;
}

extern "C" void kernel_launch(void* const* d_in, const int* in_sizes, int n_in,
                              void* d_out, int out_size, void* d_ws, size_t ws_size,
                              hipStream_t stream) {
    const float* hs    = (const float*)d_in[0];
    const float* Wq    = (const float*)d_in[1];
    const float* Wk    = (const float*)d_in[2];
    const float* Wv    = (const float*)d_in[3];
    const float* band  = (const float*)d_in[4];
    const float* fromm = (const float*)d_in[5];
    const float* tom   = (const float*)d_in[6];
    const float* fbm   = (const float*)d_in[7];
    const float* tbm   = (const float*)d_in[8];
    const int*   ra    = (const int*)d_in[9];      // harness passes integers as int32
    float* out = (float*)d_out;

    // workspace layout (bytes):
    //  [0, 12.58M)  hsb  (bf16 hidden)  -> reused by vtb after proj
    //  [12.58M, 16.12M) wtb (3x768x768 bf16)
    //  [16.12M, 53.87M) qkv (3 x (B,NH,S,D) bf16)
    //  [53.87M, 60.36M) partials (48 x 8 x 4224 f32)
    char* ws = (char*)d_ws;
    unsigned short* hsb = (unsigned short*)(ws);
    unsigned short* vtb = (unsigned short*)(ws);                 // reuse (proj done before vtrans)
    unsigned short* wtb = (unsigned short*)(ws + 12582912);
    unsigned short* qkv = (unsigned short*)(ws + 16121856);
    float* partials     = (float*)(ws + 53870592);

    k_cast_hs<<<3072, 256, 0, stream>>>(hs, hsb, 786432);
    k_wt<<<dim3(12, 12, 3), 256, 0, stream>>>(Wq, Wk, Wv, wtb);
    k_proj<<<dim3(64, 6, 3), 256, 0, stream>>>(hsb, wtb, qkv);
    k_vtrans<<<dim3(64, 24), 256, 0, stream>>>(qkv + 2 * 6291456, vtb);
    k_attn<<<1872, 256, 0, stream>>>(qkv, qkv + 6291456, vtb, ra,
                                     band, fromm, tom, fbm, tbm, out, partials);
    k_combine<<<48, 256, 0, stream>>>(partials, fromm, out);
}

// Round 7
// 117.893 us; speedup vs baseline: 1.8338x; 1.6960x over previous
//
#include <hip/hip_runtime.h>
#include <hip/hip_bf16.h>
#include <stdint.h>

// BigBird block-sparse attention, MI355X bf16-MFMA implementation.
// B=2 S=4096 H=768 NH=12 D=64 BLK=64 NB=64 R=3
#define NHD 12
#define SLEN 4096
#define DH 64
#define NBLK 64
#define HDIM 768
#define PEN -10000.0f

typedef __bf16 bf16x8 __attribute__((ext_vector_type(8)));
typedef float f32x4 __attribute__((ext_vector_type(4)));
typedef unsigned short u16x8 __attribute__((ext_vector_type(8)));

__device__ __forceinline__ unsigned short f2bf(float x) {
    union { float f; unsigned u; } v; v.f = x;
    unsigned r = v.u + 0x7fffu + ((v.u >> 16) & 1u);   // RNE
    return (unsigned short)(r >> 16);
}

// async global->LDS, 16B per lane, LDS dest = wave-uniform base + lane*16
__device__ __forceinline__ void gl2lds16(const void* g, void* l) {
    __builtin_amdgcn_global_load_lds(
        (const __attribute__((address_space(1))) void*)g,
        (__attribute__((address_space(3))) void*)l, 16, 0, 0);
}

// ---------------- cast hidden_states f32 -> bf16 ----------------
__global__ void k_cast_hs(const float* __restrict__ in, unsigned short* __restrict__ out, int n8) {
    int i = blockIdx.x * blockDim.x + threadIdx.x;
    if (i >= n8) return;
    const float4* p = (const float4*)in + (size_t)i * 2;
    float4 a = p[0], b = p[1];
    u16x8 o;
    o[0]=f2bf(a.x); o[1]=f2bf(a.y); o[2]=f2bf(a.z); o[3]=f2bf(a.w);
    o[4]=f2bf(b.x); o[5]=f2bf(b.y); o[6]=f2bf(b.z); o[7]=f2bf(b.w);
    ((u16x8*)out)[i] = o;
}

// ---------------- W (k,n) f32 -> Wt (n,k) bf16 ----------------
__global__ void k_wt(const float* __restrict__ Wq, const float* __restrict__ Wk,
                     const float* __restrict__ Wv, unsigned short* __restrict__ wt) {
    const float* W = blockIdx.z == 0 ? Wq : (blockIdx.z == 1 ? Wk : Wv);
    unsigned short* out = wt + (size_t)blockIdx.z * HDIM * HDIM;
    __shared__ float tile[64][65];
    int t = threadIdx.x;
    int k0 = blockIdx.x * 64, n0 = blockIdx.y * 64;
    int r = t >> 2, c4 = t & 3;
#pragma unroll
    for (int j = 0; j < 16; j += 4) {
        float4 v = *(const float4*)&W[(size_t)(k0 + r) * HDIM + n0 + c4 * 16 + j];
        tile[r][c4*16+j+0] = v.x; tile[r][c4*16+j+1] = v.y;
        tile[r][c4*16+j+2] = v.z; tile[r][c4*16+j+3] = v.w;
    }
    __syncthreads();
    u16x8 o0, o1;
#pragma unroll
    for (int j = 0; j < 8; ++j) o0[j] = f2bf(tile[c4*16 + j][r]);
#pragma unroll
    for (int j = 0; j < 8; ++j) o1[j] = f2bf(tile[c4*16 + 8 + j][r]);
    *(u16x8*)&out[(size_t)(n0 + r) * HDIM + k0 + c4*16]     = o0;
    *(u16x8*)&out[(size_t)(n0 + r) * HDIM + k0 + c4*16 + 8] = o1;
}

// ---------------- projection GEMM: (8192x768)x(768x768) bf16 MFMA ----------------
__global__ __launch_bounds__(256) void k_proj(const unsigned short* __restrict__ hsb,
                                              const unsigned short* __restrict__ wtb,
                                              unsigned short* __restrict__ qkv) {
    __shared__ unsigned short As[128][72];
    __shared__ unsigned short Bs[128][72];
    const unsigned short* Bw = wtb + (size_t)blockIdx.z * HDIM * HDIM;
    unsigned short* out = qkv + (size_t)blockIdx.z * (2u * NHD * SLEN * DH);
    int m0 = blockIdx.x * 128, n0 = blockIdx.y * 128;
    int t = threadIdx.x;
    int w = t >> 6, l = t & 63, g = l >> 4, c = l & 15;
    int wm = w >> 1, wn = w & 1;
    int sr = t >> 1, sh = (t & 1) * 32;
    f32x4 acc[4][4];
#pragma unroll
    for (int i = 0; i < 4; ++i)
#pragma unroll
        for (int j = 0; j < 4; ++j) acc[i][j] = (f32x4){0.f,0.f,0.f,0.f};

    for (int kt = 0; kt < HDIM; kt += 64) {
        __syncthreads();
#pragma unroll
        for (int j = 0; j < 4; ++j) {
            *(u16x8*)&As[sr][sh + 8*j] = *(const u16x8*)&hsb[(size_t)(m0 + sr) * HDIM + kt + sh + 8*j];
            *(u16x8*)&Bs[sr][sh + 8*j] = *(const u16x8*)&Bw[(size_t)(n0 + sr) * HDIM + kt + sh + 8*j];
        }
        __syncthreads();
#pragma unroll
        for (int ks = 0; ks < 2; ++ks) {
            bf16x8 af[4], bf_[4];
#pragma unroll
            for (int mt = 0; mt < 4; ++mt) af[mt]  = *(const bf16x8*)&As[64*wm + 16*mt + c][32*ks + 8*g];
#pragma unroll
            for (int nt = 0; nt < 4; ++nt) bf_[nt] = *(const bf16x8*)&Bs[64*wn + 16*nt + c][32*ks + 8*g];
#pragma unroll
            for (int mt = 0; mt < 4; ++mt)
#pragma unroll
                for (int nt = 0; nt < 4; ++nt)
                    acc[mt][nt] = __builtin_amdgcn_mfma_f32_16x16x32_bf16(af[mt], bf_[nt], acc[mt][nt], 0, 0, 0);
        }
    }
#pragma unroll
    for (int mt = 0; mt < 4; ++mt)
#pragma unroll
        for (int nt = 0; nt < 4; ++nt)
#pragma unroll
            for (int r2 = 0; r2 < 4; ++r2) {
                int m = m0 + 64*wm + 16*mt + 4*g + r2;
                int n = n0 + 64*wn + 16*nt + c;
                int bb = m >> 12, s = m & 4095;
                int hh = n >> 6,  d = n & 63;
                out[(((size_t)bb * NHD + hh) * SLEN + s) * DH + d] = f2bf(acc[mt][nt][r2]);
            }
}

// ---------------- V (bh,s,d) -> VT (bh,d,s) bf16 ----------------
__global__ void k_vtrans(const unsigned short* __restrict__ v, unsigned short* __restrict__ vt) {
    __shared__ unsigned tile[64][65];
    int bh = blockIdx.y;
    int s0 = blockIdx.x * 64;
    int t = threadIdx.x;
    int r = t >> 2, c4 = t & 3;
    const unsigned short* vb = v + (size_t)bh * SLEN * DH;
#pragma unroll
    for (int jj = 0; jj < 16; jj += 8) {
        u16x8 x = *(const u16x8*)&vb[(size_t)(s0 + r) * DH + c4*16 + jj];
#pragma unroll
        for (int e = 0; e < 8; ++e) tile[r][c4*16 + jj + e] = x[e];
    }
    __syncthreads();
    unsigned short* vto = vt + (size_t)bh * DH * SLEN;
    int d = t >> 2;
    u16x8 o0, o1;
#pragma unroll
    for (int j = 0; j < 8; ++j) o0[j] = (unsigned short)tile[c4*16 + j][d];
#pragma unroll
    for (int j = 0; j < 8; ++j) o1[j] = (unsigned short)tile[c4*16 + 8 + j][d];
    *(u16x8*)&vto[(size_t)d * SLEN + s0 + c4*16]     = o0;
    *(u16x8*)&vto[(size_t)d * SLEN + s0 + c4*16 + 8] = o1;
}

// ---------------- flash-style block-sparse attention (v6) ----------------
// v5 task decomposition + LDS-staged K/V via global_load_lds (zero VGPR
// dests; v5's 128-reg load bursts > 120 VGPR forced serialized load
// batches ~5800 cyc/step). K/V staged ONCE per block (4 waves shared,
// was 4x redundant), double-buffered: stage(t+1) issued before
// compute(t). T2 source-side XOR swizzle (slot^=row&7) -> 2-way-free
// ds_reads. Masks pipelined one step ahead into regs.
__global__ __launch_bounds__(256) void k_attn(
    const unsigned short* __restrict__ Qb, const unsigned short* __restrict__ Kb,
    const unsigned short* __restrict__ VTb,
    const int* __restrict__ rand_attn,
    const float* __restrict__ band_mask, const float* __restrict__ from_mask,
    const float* __restrict__ to_mask, const float* __restrict__ fbm,
    const float* __restrict__ tbm,
    float* __restrict__ out, float* __restrict__ partials)
{
    __shared__ __align__(16) unsigned short Kt[2][4096];   // [buf][64 keys x 64 d] 16KB
    __shared__ __align__(16) unsigned short Vt[2][4096];   // [buf][64 d x 64 keys] 16KB
    __shared__ __align__(16) char plds[4 * 2048];          // per-wave P tile 8KB

    int i0 = blockIdx.x;
    int gid = (i0 & 7) * 234 + (i0 >> 3);           // XCD swizzle (1872 = 8*234)
    int bh = gid / 78, task = gid - bh * 78;
    int b = bh / NHD, h = bh - b * NHD;
    int t = threadIdx.x;
    int wq = t >> 6, l = t & 63, g = l >> 4, c = l & 15;
    int lr = l >> 3, ls = l & 7, sw = ls ^ lr;      // stage swizzle

    // ---- task -> 8 step descriptors (kv: 0=to_mask 1=band 2=rand 3=skip) ----
    int row, mode = 0, pslot = 0;
    int blkj[8], kvj[8], sbj[8];
#pragma unroll
    for (int j = 0; j < 8; ++j) sbj[j] = 0;
    if (task < 8) {
        row = 0; mode = 1; pslot = task;
#pragma unroll
        for (int j = 0; j < 8; ++j) { blkj[j] = task * 8 + j; kvj[j] = 0; }
    } else if (task >= 70) {
        row = 63; mode = 1; pslot = task - 70;
#pragma unroll
        for (int j = 0; j < 8; ++j) { blkj[j] = pslot * 8 + j; kvj[j] = 0; }
    } else {
        row = task - 7;                              // 1..62
        int rbase = ((b * NHD + h) * 62 + (row - 1)) * 3;
        blkj[4] = rand_attn[rbase];
        blkj[5] = rand_attn[rbase + 1];
        blkj[6] = rand_attn[rbase + 2];
        kvj[4] = kvj[5] = kvj[6] = 2;
        blkj[0] = 0; kvj[0] = 0;
        if (row == 1) {
            blkj[1]=1;  blkj[2]=2;  blkj[3]=63; kvj[1]=kvj[2]=kvj[3]=0;
            blkj[7]=0;  kvj[7]=3;
        } else if (row == 62) {
            blkj[1]=61; blkj[2]=62; blkj[3]=63; kvj[1]=kvj[2]=kvj[3]=0;
            blkj[7]=0;  kvj[7]=3;
        } else {
            blkj[1]=row-1; blkj[2]=row; blkj[3]=row+1;
            kvj[1]=kvj[2]=kvj[3]=1; sbj[1]=0; sbj[2]=64; sbj[3]=128;
            blkj[7]=63; kvj[7]=0;
        }
    }

    size_t bhoff = (size_t)bh * SLEN * DH;
    const char* Kbase = (const char*)(Kb + bhoff);                  // [key][128B]
    const char* Vbase = (const char*)(VTb + (size_t)bh * DH * SLEN); // [d][8192B]
    int q0 = row * 64 + wq * 16;

    // Q fragments (held in registers whole kernel)
    bf16x8 qf[2];
#pragma unroll
    for (int kk = 0; kk < 2; ++kk)
        qf[kk] = *(const bf16x8*)&Qb[bhoff + (size_t)(q0 + c) * DH + kk * 32 + 8 * g];

    float fmq = fbm[(b * NBLK + row) * 64 + wq * 16 + c];
    size_t bm_base = ((size_t)(b * 60 + row - 2) * 64 + (wq * 16 + c)) * 192;
    int tm_base = b * SLEN;

    float m_run = -1e30f, l_run = 0.f;
    f32x4 o_acc[4];
#pragma unroll
    for (int dt = 0; dt < 4; ++dt) o_acc[dt] = (f32x4){0.f,0.f,0.f,0.f};

    char* myl = plds + wq * 2048 + c * 128;
    int swz = (c & 7) << 4;

    // ---- stage K+V tile for block blk into buffer nb (4 waves cooperate) ----
    auto stage = [&](int blk, int nb) __attribute__((always_inline)) {
#pragma unroll
        for (int ii = 0; ii < 2; ++ii) {
            int i = wq * 2 + ii;                          // chunk 0..7 (8 rows each)
            const char* ksrc = Kbase + (size_t)blk * 8192 + (size_t)(i*8 + lr) * 128 + sw * 16;
            gl2lds16(ksrc, (char*)&Kt[nb][0] + i * 1024);
            const char* vsrc = Vbase + (size_t)(i*8 + lr) * 8192 + (size_t)blk * 128 + sw * 16;
            gl2lds16(vsrc, (char*)&Vt[nb][0] + i * 1024);
        }
    };

    auto loadmask = [&](int kv, int blk, int sb, float4* mk) __attribute__((always_inline)) {
        if (kv == 0) {
#pragma unroll
            for (int mt = 0; mt < 4; ++mt)
                mk[mt] = *(const float4*)&to_mask[tm_base + blk * 64 + mt * 16 + 4 * g];
        } else if (kv == 1) {
#pragma unroll
            for (int mt = 0; mt < 4; ++mt)
                mk[mt] = *(const float4*)&band_mask[bm_base + sb + mt * 16 + 4 * g];
        } else if (kv == 2) {
#pragma unroll
            for (int mt = 0; mt < 4; ++mt)
                mk[mt] = *(const float4*)&tbm[(size_t)(b * NBLK + blk) * 64 + mt * 16 + 4 * g];
        }
    };

    auto compute = [&](int kv, int nb, const float4* mk) __attribute__((always_inline)) {
        if (kv == 3) return;                              // block-uniform skip (pad step)
        int c7 = c & 7;
        // ---- K frags from LDS (swizzled: slot = (kk*4+g)^(c&7)) ----
        bf16x8 kf[4][2];
#pragma unroll
        for (int mt = 0; mt < 4; ++mt)
#pragma unroll
            for (int kk = 0; kk < 2; ++kk)
                kf[mt][kk] = *(const bf16x8*)((const char*)&Kt[nb][0]
                              + (mt*16 + c) * 128 + (((kk*4 + g) ^ c7) * 16));

        // ---- S^T = K * Q^T ----
        f32x4 sa[4];
#pragma unroll
        for (int mt = 0; mt < 4; ++mt) sa[mt] = (f32x4){0.f,0.f,0.f,0.f};
#pragma unroll
        for (int kk = 0; kk < 2; ++kk)
#pragma unroll
            for (int mt = 0; mt < 4; ++mt)
                sa[mt] = __builtin_amdgcn_mfma_f32_16x16x32_bf16(kf[mt][kk], qf[kk], sa[mt], 0, 0, 0);

        // ---- scale + penalty (kv==2 folds fmq) ----
        float fmk = (kv == 2) ? fmq : 1.f;
#pragma unroll
        for (int mt = 0; mt < 4; ++mt) {
            sa[mt][0] = sa[mt][0] * 0.125f + (1.f - fmk * mk[mt].x) * PEN;
            sa[mt][1] = sa[mt][1] * 0.125f + (1.f - fmk * mk[mt].y) * PEN;
            sa[mt][2] = sa[mt][2] * 0.125f + (1.f - fmk * mk[mt].z) * PEN;
            sa[mt][3] = sa[mt][3] * 0.125f + (1.f - fmk * mk[mt].w) * PEN;
        }

        // ---- online softmax (defer-max, THR=8) ----
        float pm = -1e30f;
#pragma unroll
        for (int mt = 0; mt < 4; ++mt)
#pragma unroll
            for (int r2 = 0; r2 < 4; ++r2) pm = fmaxf(pm, sa[mt][r2]);
        pm = fmaxf(pm, __shfl_xor(pm, 16));
        pm = fmaxf(pm, __shfl_xor(pm, 32));
        bool need = pm > m_run + 8.f;
        float mnew = need ? pm : m_run;
        float scale = __expf(m_run - mnew);
        m_run = mnew;
        l_run *= scale;
#pragma unroll
        for (int dt = 0; dt < 4; ++dt)
#pragma unroll
            for (int r2 = 0; r2 < 4; ++r2) o_acc[dt][r2] *= scale;

        float rs = 0.f;
#pragma unroll
        for (int mt = 0; mt < 4; ++mt)
#pragma unroll
            for (int r2 = 0; r2 < 4; ++r2) {
                float e = __expf(sa[mt][r2] - m_run);
                sa[mt][r2] = e;
                rs += e;
            }
        rs += __shfl_xor(rs, 16);
        rs += __shfl_xor(rs, 32);
        l_run += rs;

        // ---- pack P -> wave-private LDS, read back as B-frags ----
#pragma unroll
        for (int mt = 0; mt < 4; ++mt) {
            unsigned lo = (unsigned)f2bf(sa[mt][0]) | ((unsigned)f2bf(sa[mt][1]) << 16);
            unsigned hi = (unsigned)f2bf(sa[mt][2]) | ((unsigned)f2bf(sa[mt][3]) << 16);
            unsigned long long pk = (unsigned long long)lo | ((unsigned long long)hi << 32);
            *(unsigned long long*)(myl + ((mt * 32 + g * 8) ^ swz)) = pk;
        }
        asm volatile("" ::: "memory");
        bf16x8 pf0 = *(const bf16x8*)(myl + ((g * 16) ^ swz));
        bf16x8 pf1 = *(const bf16x8*)(myl + ((64 + g * 16) ^ swz));

        // ---- O^T += V^T * P  (V frags from LDS, swizzled) ----
#pragma unroll
        for (int dt = 0; dt < 4; ++dt) {
            bf16x8 v0 = *(const bf16x8*)((const char*)&Vt[nb][0]
                          + (dt*16 + c) * 128 + ((g ^ c7) * 16));
            bf16x8 v1 = *(const bf16x8*)((const char*)&Vt[nb][0]
                          + (dt*16 + c) * 128 + (((4 + g) ^ c7) * 16));
            o_acc[dt] = __builtin_amdgcn_mfma_f32_16x16x32_bf16(v0, pf0, o_acc[dt], 0, 0, 0);
            o_acc[dt] = __builtin_amdgcn_mfma_f32_16x16x32_bf16(v1, pf1, o_acc[dt], 0, 0, 0);
        }
    };

    // ---- pipelined 8-step loop (stage t+1 ahead of compute t) ----
    float4 mkA[4], mkB[4];
    stage(blkj[0], 0);
    loadmask(kvj[0], blkj[0], sbj[0], mkA);
    __syncthreads();                                  // drains vmcnt(0) too
#pragma unroll
    for (int tt = 0; tt < 8; ++tt) {
        if (tt < 7) {
            stage(blkj[tt + 1], (tt & 1) ^ 1);
            loadmask(kvj[tt + 1], blkj[tt + 1], sbj[tt + 1], (tt & 1) ? mkA : mkB);
        }
        compute(kvj[tt], tt & 1, (tt & 1) ? mkB : mkA);
        __syncthreads();                              // tile t+1 landed; all waves done with buf
    }

    if (mode == 0) {
        int s = q0 + c;
        float fm = from_mask[b * SLEN + s];
        float inv = fm / l_run;
        size_t obase = ((size_t)b * SLEN + s) * HDIM + h * DH;
#pragma unroll
        for (int dt = 0; dt < 4; ++dt) {
            float4 val;
            val.x = o_acc[dt][0] * inv;
            val.y = o_acc[dt][1] * inv;
            val.z = o_acc[dt][2] * inv;
            val.w = o_acc[dt][3] * inv;
            *(float4*)&out[obase + dt * 16 + 4 * g] = val;
        }
    } else {
        float* pb = partials + (size_t)((bh * 2 + (row == 63 ? 1 : 0)) * 8 + pslot) * 4224;
        int q = wq * 16 + c;
#pragma unroll
        for (int dt = 0; dt < 4; ++dt) {
            float4 val;
            val.x = o_acc[dt][0]; val.y = o_acc[dt][1];
            val.z = o_acc[dt][2]; val.w = o_acc[dt][3];
            *(float4*)&pb[q * 64 + dt * 16 + 4 * g] = val;
        }
        if (g == 0) {
            pb[4096 + q] = m_run;
            pb[4160 + q] = l_run;
        }
    }
}

// ---------------- combine 8 partials for row-blocks 0 and 63 ----------------
__global__ void k_combine(const float* __restrict__ partials, const float* __restrict__ from_mask,
                          float* __restrict__ out) {
    int gid = blockIdx.x;          // 48 = bh*2 + rb
    int bh = gid >> 1, rb = gid & 1;
    int b = bh / NHD, h = bh - b * NHD;
    int t = threadIdx.x;           // 256
    int q = t >> 2, dc = (t & 3) * 16;
    const float* base = partials + (size_t)gid * 8 * 4224;
    float M = -1e30f;
#pragma unroll
    for (int i = 0; i < 8; ++i) M = fmaxf(M, base[i*4224 + 4096 + q]);
    float L = 0.f, cx[16];
#pragma unroll
    for (int j = 0; j < 16; ++j) cx[j] = 0.f;
    for (int i = 0; i < 8; ++i) {
        float w = __expf(base[i*4224 + 4096 + q] - M);
        L += base[i*4224 + 4160 + q] * w;
#pragma unroll
        for (int j = 0; j < 16; ++j) cx[j] += base[i*4224 + q*64 + dc + j] * w;
    }
    int s = (rb ? 4032 : 0) + q;
    float fm = from_mask[b * SLEN + s];
    float inv = fm / L;
#pragma unroll
    for (int j = 0; j < 16; ++j)
        out[((size_t)b * SLEN + s) * HDIM + h * DH + dc + j] = cx[j] * inv;
}

extern "C" void kernel_launch(void* const* d_in, const int* in_sizes, int n_in,
                              void* d_out, int out_size, void* d_ws, size_t ws_size,
                              hipStream_t stream) {
    const float* hs    = (const float*)d_in[0];
    const float* Wq    = (const float*)d_in[1];
    const float* Wk    = (const float*)d_in[2];
    const float* Wv    = (const float*)d_in[3];
    const float* band  = (const float*)d_in[4];
    const float* fromm = (const float*)d_in[5];
    const float* tom   = (const float*)d_in[6];
    const float* fbm   = (const float*)d_in[7];
    const float* tbm   = (const float*)d_in[8];
    const int*   ra    = (const int*)d_in[9];      // harness passes integers as int32
    float* out = (float*)d_out;

    // workspace layout (bytes):
    //  [0, 12.58M)  hsb  (bf16 hidden)  -> reused by vtb after proj
    //  [12.58M, 16.12M) wtb (3x768x768 bf16)
    //  [16.12M, 53.87M) qkv (3 x (B,NH,S,D) bf16)
    //  [53.87M, 60.36M) partials (48 x 8 x 4224 f32)
    char* ws = (char*)d_ws;
    unsigned short* hsb = (unsigned short*)(ws);
    unsigned short* vtb = (unsigned short*)(ws);                 // reuse (proj done before vtrans)
    unsigned short* wtb = (unsigned short*)(ws + 12582912);
    unsigned short* qkv = (unsigned short*)(ws + 16121856);
    float* partials     = (float*)(ws + 53870592);

    k_cast_hs<<<3072, 256, 0, stream>>>(hs, hsb, 786432);
    k_wt<<<dim3(12, 12, 3), 256, 0, stream>>>(Wq, Wk, Wv, wtb);
    k_proj<<<dim3(64, 6, 3), 256, 0, stream>>>(hsb, wtb, qkv);
    k_vtrans<<<dim3(64, 24), 256, 0, stream>>>(qkv + 2 * 6291456, vtb);
    k_attn<<<1872, 256, 0, stream>>>(qkv, qkv + 6291456, vtb, ra,
                                     band, fromm, tom, fbm, tbm, out, partials);
    k_combine<<<48, 256, 0, stream>>>(partials, fromm, out);
}

// Round 8
// 109.653 us; speedup vs baseline: 1.9716x; 1.0751x over previous
//
#include <hip/hip_runtime.h>
#include <hip/hip_bf16.h>
#include <stdint.h>

// BigBird block-sparse attention, MI355X bf16-MFMA implementation.
// B=2 S=4096 H=768 NH=12 D=64 BLK=64 NB=64 R=3
#define NHD 12
#define SLEN 4096
#define DH 64
#define NBLK 64
#define HDIM 768
#define PEN -10000.0f
#define LOG2E 1.44269504f

typedef __bf16 bf16x8 __attribute__((ext_vector_type(8)));
typedef float f32x4 __attribute__((ext_vector_type(4)));
typedef unsigned short u16x8 __attribute__((ext_vector_type(8)));

__device__ __forceinline__ unsigned short f2bf(float x) {
    union { float f; unsigned u; } v; v.f = x;
    unsigned r = v.u + 0x7fffu + ((v.u >> 16) & 1u);   // RNE
    return (unsigned short)(r >> 16);
}

// async global->LDS, 16B per lane, LDS dest = wave-uniform base + lane*16
__device__ __forceinline__ void gl2lds16(const void* g, void* l) {
    __builtin_amdgcn_global_load_lds(
        (const __attribute__((address_space(1))) void*)g,
        (__attribute__((address_space(3))) void*)l, 16, 0, 0);
}

// ---------------- cast hidden_states f32 -> bf16 ----------------
__global__ void k_cast_hs(const float* __restrict__ in, unsigned short* __restrict__ out, int n8) {
    int i = blockIdx.x * blockDim.x + threadIdx.x;
    if (i >= n8) return;
    const float4* p = (const float4*)in + (size_t)i * 2;
    float4 a = p[0], b = p[1];
    u16x8 o;
    o[0]=f2bf(a.x); o[1]=f2bf(a.y); o[2]=f2bf(a.z); o[3]=f2bf(a.w);
    o[4]=f2bf(b.x); o[5]=f2bf(b.y); o[6]=f2bf(b.z); o[7]=f2bf(b.w);
    ((u16x8*)out)[i] = o;
}

// ---------------- W (k,n) f32 -> Wt (n,k) bf16 ----------------
__global__ void k_wt(const float* __restrict__ Wq, const float* __restrict__ Wk,
                     const float* __restrict__ Wv, unsigned short* __restrict__ wt) {
    const float* W = blockIdx.z == 0 ? Wq : (blockIdx.z == 1 ? Wk : Wv);
    unsigned short* out = wt + (size_t)blockIdx.z * HDIM * HDIM;
    __shared__ float tile[64][65];
    int t = threadIdx.x;
    int k0 = blockIdx.x * 64, n0 = blockIdx.y * 64;
    int r = t >> 2, c4 = t & 3;
#pragma unroll
    for (int j = 0; j < 16; j += 4) {
        float4 v = *(const float4*)&W[(size_t)(k0 + r) * HDIM + n0 + c4 * 16 + j];
        tile[r][c4*16+j+0] = v.x; tile[r][c4*16+j+1] = v.y;
        tile[r][c4*16+j+2] = v.z; tile[r][c4*16+j+3] = v.w;
    }
    __syncthreads();
    u16x8 o0, o1;
#pragma unroll
    for (int j = 0; j < 8; ++j) o0[j] = f2bf(tile[c4*16 + j][r]);
#pragma unroll
    for (int j = 0; j < 8; ++j) o1[j] = f2bf(tile[c4*16 + 8 + j][r]);
    *(u16x8*)&out[(size_t)(n0 + r) * HDIM + k0 + c4*16]     = o0;
    *(u16x8*)&out[(size_t)(n0 + r) * HDIM + k0 + c4*16 + 8] = o1;
}

// ---------------- projection GEMM (m97 structure) ----------------
// 128x128 tile, BK=64, global_load_lds staging (source-side XOR swizzle,
// linear LDS dest), 32KB LDS, 2 barriers/K-tile. TR=false: out (bh,s,d)
// for Q/K. TR=true: operands swapped in MFMA -> acc rows = n(d), cols =
// m(s); writes V^T (bh,d,s) directly (k_vtrans eliminated).
template<bool TR>
__global__ __launch_bounds__(256) void k_proj(const unsigned short* __restrict__ hsb,
                                              const unsigned short* __restrict__ wtb,
                                              unsigned short* __restrict__ outbuf) {
    __shared__ __align__(16) unsigned short As[8192];   // [128 rows][128B], swizzled slots
    __shared__ __align__(16) unsigned short Bs[8192];
    const char* Abase = (const char*)hsb;
    const char* Bbase = (const char*)(wtb + (size_t)blockIdx.z * HDIM * HDIM);
    unsigned short* out = outbuf + (size_t)blockIdx.z * (2u * NHD * SLEN * DH);
    int m0 = blockIdx.x * 128, n0 = blockIdx.y * 128;
    int t = threadIdx.x;
    int w = t >> 6, l = t & 63, g = l >> 4, c = l & 15;
    int wm = w >> 1, wn = w & 1;
    int lr = l >> 3, ls = l & 7, sw = ls ^ lr;          // stage swizzle (slot ^= row&7)
    int c7 = c & 7;
    f32x4 acc[4][4];
#pragma unroll
    for (int i = 0; i < 4; ++i)
#pragma unroll
        for (int j = 0; j < 4; ++j) acc[i][j] = (f32x4){0.f,0.f,0.f,0.f};

    for (int kt = 0; kt < HDIM; kt += 64) {
        __syncthreads();
#pragma unroll
        for (int i = 0; i < 4; ++i) {
            int rowb = w * 32 + i * 8;                   // 8 rows per issue
            gl2lds16(Abase + (size_t)(m0 + rowb + lr) * 1536 + kt * 2 + sw * 16,
                     (char*)As + rowb * 128);
            gl2lds16(Bbase + (size_t)(n0 + rowb + lr) * 1536 + kt * 2 + sw * 16,
                     (char*)Bs + rowb * 128);
        }
        __syncthreads();                                 // drains vmcnt before reads
#pragma unroll
        for (int ks = 0; ks < 2; ++ks) {
            bf16x8 af[4], bf_[4];
#pragma unroll
            for (int mt = 0; mt < 4; ++mt)
                af[mt]  = *(const bf16x8*)((const char*)As
                            + (64*wm + 16*mt + c) * 128 + (((ks*4 + g) ^ c7) * 16));
#pragma unroll
            for (int nt = 0; nt < 4; ++nt)
                bf_[nt] = *(const bf16x8*)((const char*)Bs
                            + (64*wn + 16*nt + c) * 128 + (((ks*4 + g) ^ c7) * 16));
#pragma unroll
            for (int i = 0; i < 4; ++i)
#pragma unroll
                for (int j = 0; j < 4; ++j)
                    acc[i][j] = TR
                        ? __builtin_amdgcn_mfma_f32_16x16x32_bf16(bf_[i], af[j], acc[i][j], 0, 0, 0)
                        : __builtin_amdgcn_mfma_f32_16x16x32_bf16(af[i], bf_[j], acc[i][j], 0, 0, 0);
        }
    }
#pragma unroll
    for (int i = 0; i < 4; ++i)
#pragma unroll
        for (int j = 0; j < 4; ++j)
#pragma unroll
            for (int r2 = 0; r2 < 4; ++r2) {
                if (!TR) {
                    int m = m0 + 64*wm + 16*i + 4*g + r2;     // s-dim (acc row)
                    int n = n0 + 64*wn + 16*j + c;            // h*64+d (acc col)
                    int bb = m >> 12, s = m & 4095;
                    int hh = n >> 6,  d = n & 63;
                    out[(((size_t)bb * NHD + hh) * SLEN + s) * DH + d] = f2bf(acc[i][j][r2]);
                } else {
                    int n = n0 + 64*wn + 16*i + 4*g + r2;     // h*64+d (acc row)
                    int m = m0 + 64*wm + 16*j + c;            // s-dim (acc col)
                    int bb = m >> 12, s = m & 4095;
                    int hh = n >> 6,  d = n & 63;
                    out[(((size_t)bb * NHD + hh) * DH + d) * SLEN + s] = f2bf(acc[i][j][r2]);
                }
            }
}

// ---------------- flash-style block-sparse attention (v7) ----------------
// v6 staged-dbuf structure + VALU-chain diet: exp2-domain softmax (fold
// log2e into scale+penalty; exp2f = bare v_exp_f32), penalties precomputed
// in the pipelined mask phase, ballot-gated defer-max rescale skip, and
// native (__bf16) casts for the P-pack (v_cvt_pk_bf16_f32, same RNE).
__global__ __launch_bounds__(256) void k_attn(
    const unsigned short* __restrict__ Qb, const unsigned short* __restrict__ Kb,
    const unsigned short* __restrict__ VTb,
    const int* __restrict__ rand_attn,
    const float* __restrict__ band_mask, const float* __restrict__ from_mask,
    const float* __restrict__ to_mask, const float* __restrict__ fbm,
    const float* __restrict__ tbm,
    float* __restrict__ out, float* __restrict__ partials)
{
    __shared__ __align__(16) unsigned short Kt[2][4096];   // [buf][64 keys x 64 d] 16KB
    __shared__ __align__(16) unsigned short Vt[2][4096];   // [buf][64 d x 64 keys] 16KB
    __shared__ __align__(16) char plds[4 * 2048];          // per-wave P tile 8KB

    const float SC = 0.125f * LOG2E;          // qk scale in log2 domain
    const float PL = PEN * LOG2E;             // penalty in log2 domain
    const float THR2 = 8.0f * LOG2E;          // defer-max threshold (log2)

    int i0 = blockIdx.x;
    int gid = (i0 & 7) * 234 + (i0 >> 3);           // XCD swizzle (1872 = 8*234)
    int bh = gid / 78, task = gid - bh * 78;
    int b = bh / NHD, h = bh - b * NHD;
    int t = threadIdx.x;
    int wq = t >> 6, l = t & 63, g = l >> 4, c = l & 15;
    int lr = l >> 3, ls = l & 7, sw = ls ^ lr;      // stage swizzle

    // ---- task -> 8 step descriptors (kv: 0=to_mask 1=band 2=rand 3=skip) ----
    int row, mode = 0, pslot = 0;
    int blkj[8], kvj[8], sbj[8];
#pragma unroll
    for (int j = 0; j < 8; ++j) sbj[j] = 0;
    if (task < 8) {
        row = 0; mode = 1; pslot = task;
#pragma unroll
        for (int j = 0; j < 8; ++j) { blkj[j] = task * 8 + j; kvj[j] = 0; }
    } else if (task >= 70) {
        row = 63; mode = 1; pslot = task - 70;
#pragma unroll
        for (int j = 0; j < 8; ++j) { blkj[j] = pslot * 8 + j; kvj[j] = 0; }
    } else {
        row = task - 7;                              // 1..62
        int rbase = ((b * NHD + h) * 62 + (row - 1)) * 3;
        blkj[4] = rand_attn[rbase];
        blkj[5] = rand_attn[rbase + 1];
        blkj[6] = rand_attn[rbase + 2];
        kvj[4] = kvj[5] = kvj[6] = 2;
        blkj[0] = 0; kvj[0] = 0;
        if (row == 1) {
            blkj[1]=1;  blkj[2]=2;  blkj[3]=63; kvj[1]=kvj[2]=kvj[3]=0;
            blkj[7]=0;  kvj[7]=3;
        } else if (row == 62) {
            blkj[1]=61; blkj[2]=62; blkj[3]=63; kvj[1]=kvj[2]=kvj[3]=0;
            blkj[7]=0;  kvj[7]=3;
        } else {
            blkj[1]=row-1; blkj[2]=row; blkj[3]=row+1;
            kvj[1]=kvj[2]=kvj[3]=1; sbj[1]=0; sbj[2]=64; sbj[3]=128;
            blkj[7]=63; kvj[7]=0;
        }
    }

    size_t bhoff = (size_t)bh * SLEN * DH;
    const char* Kbase = (const char*)(Kb + bhoff);                  // [key][128B]
    const char* Vbase = (const char*)(VTb + (size_t)bh * DH * SLEN); // [d][8192B]
    int q0 = row * 64 + wq * 16;

    // Q fragments (held in registers whole kernel)
    bf16x8 qf[2];
#pragma unroll
    for (int kk = 0; kk < 2; ++kk)
        qf[kk] = *(const bf16x8*)&Qb[bhoff + (size_t)(q0 + c) * DH + kk * 32 + 8 * g];

    float fmq = fbm[(b * NBLK + row) * 64 + wq * 16 + c];
    size_t bm_base = ((size_t)(b * 60 + row - 2) * 64 + (wq * 16 + c)) * 192;
    int tm_base = b * SLEN;

    float m_run = -1e30f, l_run = 0.f;
    f32x4 o_acc[4];
#pragma unroll
    for (int dt = 0; dt < 4; ++dt) o_acc[dt] = (f32x4){0.f,0.f,0.f,0.f};

    char* myl = plds + wq * 2048 + c * 128;
    int swz = (c & 7) << 4;

    // ---- stage K+V tile for block blk into buffer nb (4 waves cooperate) ----
    auto stage = [&](int blk, int nb) __attribute__((always_inline)) {
#pragma unroll
        for (int ii = 0; ii < 2; ++ii) {
            int i = wq * 2 + ii;                          // chunk 0..7 (8 rows each)
            const char* ksrc = Kbase + (size_t)blk * 8192 + (size_t)(i*8 + lr) * 128 + sw * 16;
            gl2lds16(ksrc, (char*)&Kt[nb][0] + i * 1024);
            const char* vsrc = Vbase + (size_t)(i*8 + lr) * 8192 + (size_t)blk * 128 + sw * 16;
            gl2lds16(vsrc, (char*)&Vt[nb][0] + i * 1024);
        }
    };

    // ---- mask -> precomputed penalty (log2 domain), overlapped ahead ----
    auto loadpen = [&](int kv, int blk, int sb, float4* pen) __attribute__((always_inline)) {
        if (kv == 0) {
#pragma unroll
            for (int mt = 0; mt < 4; ++mt) {
                float4 mk = *(const float4*)&to_mask[tm_base + blk * 64 + mt * 16 + 4 * g];
                pen[mt].x = (1.f - mk.x) * PL; pen[mt].y = (1.f - mk.y) * PL;
                pen[mt].z = (1.f - mk.z) * PL; pen[mt].w = (1.f - mk.w) * PL;
            }
        } else if (kv == 1) {
#pragma unroll
            for (int mt = 0; mt < 4; ++mt) {
                float4 mk = *(const float4*)&band_mask[bm_base + sb + mt * 16 + 4 * g];
                pen[mt].x = (1.f - mk.x) * PL; pen[mt].y = (1.f - mk.y) * PL;
                pen[mt].z = (1.f - mk.z) * PL; pen[mt].w = (1.f - mk.w) * PL;
            }
        } else if (kv == 2) {
#pragma unroll
            for (int mt = 0; mt < 4; ++mt) {
                float4 tb = *(const float4*)&tbm[(size_t)(b * NBLK + blk) * 64 + mt * 16 + 4 * g];
                pen[mt].x = (1.f - fmq * tb.x) * PL; pen[mt].y = (1.f - fmq * tb.y) * PL;
                pen[mt].z = (1.f - fmq * tb.z) * PL; pen[mt].w = (1.f - fmq * tb.w) * PL;
            }
        }
    };

    auto compute = [&](int kv, int nb, const float4* pen) __attribute__((always_inline)) {
        if (kv == 3) return;                              // block-uniform skip (pad step)
        int c7 = c & 7;
        // ---- K frags from LDS (swizzled: slot = (kk*4+g)^(c&7)) ----
        bf16x8 kf[4][2];
#pragma unroll
        for (int mt = 0; mt < 4; ++mt)
#pragma unroll
            for (int kk = 0; kk < 2; ++kk)
                kf[mt][kk] = *(const bf16x8*)((const char*)&Kt[nb][0]
                              + (mt*16 + c) * 128 + (((kk*4 + g) ^ c7) * 16));

        // ---- S^T = K * Q^T ----
        f32x4 sa[4];
#pragma unroll
        for (int mt = 0; mt < 4; ++mt) sa[mt] = (f32x4){0.f,0.f,0.f,0.f};
#pragma unroll
        for (int kk = 0; kk < 2; ++kk)
#pragma unroll
            for (int mt = 0; mt < 4; ++mt)
                sa[mt] = __builtin_amdgcn_mfma_f32_16x16x32_bf16(kf[mt][kk], qf[kk], sa[mt], 0, 0, 0);

        // ---- scale + penalty (log2 domain, penalty precomputed) ----
#pragma unroll
        for (int mt = 0; mt < 4; ++mt) {
            sa[mt][0] = sa[mt][0] * SC + pen[mt].x;
            sa[mt][1] = sa[mt][1] * SC + pen[mt].y;
            sa[mt][2] = sa[mt][2] * SC + pen[mt].z;
            sa[mt][3] = sa[mt][3] * SC + pen[mt].w;
        }

        // ---- online softmax (defer-max THR, ballot-gated rescale) ----
        float pm = -1e30f;
#pragma unroll
        for (int mt = 0; mt < 4; ++mt)
#pragma unroll
            for (int r2 = 0; r2 < 4; ++r2) pm = fmaxf(pm, sa[mt][r2]);
        pm = fmaxf(pm, __shfl_xor(pm, 16));
        pm = fmaxf(pm, __shfl_xor(pm, 32));
        if (__ballot(pm > m_run + THR2)) {
            bool need = pm > m_run + THR2;
            float mnew = need ? pm : m_run;
            float scale = exp2f(m_run - mnew);
            m_run = mnew;
            l_run *= scale;
#pragma unroll
            for (int dt = 0; dt < 4; ++dt)
#pragma unroll
                for (int r2 = 0; r2 < 4; ++r2) o_acc[dt][r2] *= scale;
        }

        float rs = 0.f;
#pragma unroll
        for (int mt = 0; mt < 4; ++mt)
#pragma unroll
            for (int r2 = 0; r2 < 4; ++r2) {
                float e = exp2f(sa[mt][r2] - m_run);
                sa[mt][r2] = e;
                rs += e;
            }
        rs += __shfl_xor(rs, 16);
        rs += __shfl_xor(rs, 32);
        l_run += rs;

        // ---- pack P -> wave-private LDS (native bf16 casts), read back ----
#pragma unroll
        for (int mt = 0; mt < 4; ++mt) {
            union { __bf16 hh[4]; unsigned long long u; } pk_;
            pk_.hh[0] = (__bf16)sa[mt][0]; pk_.hh[1] = (__bf16)sa[mt][1];
            pk_.hh[2] = (__bf16)sa[mt][2]; pk_.hh[3] = (__bf16)sa[mt][3];
            *(unsigned long long*)(myl + ((mt * 32 + g * 8) ^ swz)) = pk_.u;
        }
        asm volatile("" ::: "memory");
        bf16x8 pf0 = *(const bf16x8*)(myl + ((g * 16) ^ swz));
        bf16x8 pf1 = *(const bf16x8*)(myl + ((64 + g * 16) ^ swz));

        // ---- O^T += V^T * P  (V frags from LDS, swizzled) ----
#pragma unroll
        for (int dt = 0; dt < 4; ++dt) {
            bf16x8 v0 = *(const bf16x8*)((const char*)&Vt[nb][0]
                          + (dt*16 + c) * 128 + ((g ^ c7) * 16));
            bf16x8 v1 = *(const bf16x8*)((const char*)&Vt[nb][0]
                          + (dt*16 + c) * 128 + (((4 + g) ^ c7) * 16));
            o_acc[dt] = __builtin_amdgcn_mfma_f32_16x16x32_bf16(v0, pf0, o_acc[dt], 0, 0, 0);
            o_acc[dt] = __builtin_amdgcn_mfma_f32_16x16x32_bf16(v1, pf1, o_acc[dt], 0, 0, 0);
        }
    };

    // ---- pipelined 8-step loop (stage t+1 ahead of compute t) ----
    float4 penA[4], penB[4];
    stage(blkj[0], 0);
    loadpen(kvj[0], blkj[0], sbj[0], penA);
    __syncthreads();                                  // drains vmcnt(0) too
#pragma unroll
    for (int tt = 0; tt < 8; ++tt) {
        if (tt < 7) {
            stage(blkj[tt + 1], (tt & 1) ^ 1);
            loadpen(kvj[tt + 1], blkj[tt + 1], sbj[tt + 1], (tt & 1) ? penA : penB);
        }
        compute(kvj[tt], tt & 1, (tt & 1) ? penB : penA);
        __syncthreads();                              // tile t+1 landed; all waves done with buf
    }

    if (mode == 0) {
        int s = q0 + c;
        float fm = from_mask[b * SLEN + s];
        float inv = fm / l_run;
        size_t obase = ((size_t)b * SLEN + s) * HDIM + h * DH;
#pragma unroll
        for (int dt = 0; dt < 4; ++dt) {
            float4 val;
            val.x = o_acc[dt][0] * inv;
            val.y = o_acc[dt][1] * inv;
            val.z = o_acc[dt][2] * inv;
            val.w = o_acc[dt][3] * inv;
            *(float4*)&out[obase + dt * 16 + 4 * g] = val;
        }
    } else {
        float* pb = partials + (size_t)((bh * 2 + (row == 63 ? 1 : 0)) * 8 + pslot) * 4224;
        int q = wq * 16 + c;
#pragma unroll
        for (int dt = 0; dt < 4; ++dt) {
            float4 val;
            val.x = o_acc[dt][0]; val.y = o_acc[dt][1];
            val.z = o_acc[dt][2]; val.w = o_acc[dt][3];
            *(float4*)&pb[q * 64 + dt * 16 + 4 * g] = val;
        }
        if (g == 0) {
            pb[4096 + q] = m_run;                     // log2 domain
            pb[4160 + q] = l_run;
        }
    }
}

// ---------------- combine 8 partials for row-blocks 0 and 63 ----------------
// partial o_i is raw (unnormalized); m_i in log2 domain -> weight exp2(m_i-M).
__global__ void k_combine(const float* __restrict__ partials, const float* __restrict__ from_mask,
                          float* __restrict__ out) {
    int gid = blockIdx.x;          // 48 = bh*2 + rb
    int bh = gid >> 1, rb = gid & 1;
    int b = bh / NHD, h = bh - b * NHD;
    int t = threadIdx.x;           // 256
    int q = t >> 2, dc = (t & 3) * 16;
    const float* base = partials + (size_t)gid * 8 * 4224;
    float M = -1e30f;
#pragma unroll
    for (int i = 0; i < 8; ++i) M = fmaxf(M, base[i*4224 + 4096 + q]);
    float L = 0.f, cx[16];
#pragma unroll
    for (int j = 0; j < 16; ++j) cx[j] = 0.f;
    for (int i = 0; i < 8; ++i) {
        float w = exp2f(base[i*4224 + 4096 + q] - M);
        L += base[i*4224 + 4160 + q] * w;
#pragma unroll
        for (int j = 0; j < 16; ++j) cx[j] += base[i*4224 + q*64 + dc + j] * w;
    }
    int s = (rb ? 4032 : 0) + q;
    float fm = from_mask[b * SLEN + s];
    float inv = fm / L;
#pragma unroll
    for (int j = 0; j < 16; ++j)
        out[((size_t)b * SLEN + s) * HDIM + h * DH + dc + j] = cx[j] * inv;
}

extern "C" void kernel_launch(void* const* d_in, const int* in_sizes, int n_in,
                              void* d_out, int out_size, void* d_ws, size_t ws_size,
                              hipStream_t stream) {
    const float* hs    = (const float*)d_in[0];
    const float* Wq    = (const float*)d_in[1];
    const float* Wk    = (const float*)d_in[2];
    const float* Wv    = (const float*)d_in[3];
    const float* band  = (const float*)d_in[4];
    const float* fromm = (const float*)d_in[5];
    const float* tom   = (const float*)d_in[6];
    const float* fbm   = (const float*)d_in[7];
    const float* tbm   = (const float*)d_in[8];
    const int*   ra    = (const int*)d_in[9];      // harness passes integers as int32
    float* out = (float*)d_out;

    // workspace layout (bytes):
    //  [0, 12.58M)  hsb  (bf16 hidden)
    //  [12.58M, 16.12M) wtb (3x768x768 bf16)
    //  [16.12M, 53.87M) qkv: z=0 Q (bh,s,d), z=1 K (bh,s,d), z=2 V^T (bh,d,s)
    //  [53.87M, 60.36M) partials (48 x 8 x 4224 f32)
    char* ws = (char*)d_ws;
    unsigned short* hsb = (unsigned short*)(ws);
    unsigned short* wtb = (unsigned short*)(ws + 12582912);
    unsigned short* qkv = (unsigned short*)(ws + 16121856);
    float* partials     = (float*)(ws + 53870592);

    k_cast_hs<<<3072, 256, 0, stream>>>(hs, hsb, 786432);
    k_wt<<<dim3(12, 12, 3), 256, 0, stream>>>(Wq, Wk, Wv, wtb);
    k_proj<false><<<dim3(64, 6, 2), 256, 0, stream>>>(hsb, wtb, qkv);
    k_proj<true><<<dim3(64, 6, 1), 256, 0, stream>>>(hsb, wtb + 2 * HDIM * HDIM,
                                                     qkv + 2 * 6291456);
    k_attn<<<1872, 256, 0, stream>>>(qkv, qkv + 6291456, qkv + 2 * 6291456, ra,
                                     band, fromm, tom, fbm, tbm, out, partials);
    k_combine<<<48, 256, 0, stream>>>(partials, fromm, out);
}